// Round 2
// baseline (9349.445 us; speedup 1.0000x reference)
//
#include <hip/hip_runtime.h>
#include <hip/hip_bf16.h>

constexpr int NSEQ = 4096;
constexpr int EMB  = 1024;
constexpr int NH   = 16;
constexpr int HD   = 32;       // head dim
constexpr int NL   = 6;
constexpr int HV   = NH * HD;  // 512
constexpr int FF   = 2 * EMB;  // 2048

// ---------------- embedding: z = table[ctx] + pos (all f32) ----------------
__global__ __launch_bounds__(256) void embed_kernel(const int* __restrict__ ctx,
    const float* __restrict__ table, const float* __restrict__ pos, float* __restrict__ z){
  int t = blockIdx.x * 256 + threadIdx.x;   // one thread per 4 elements
  int n = t >> 8;                            // EMB/4 = 256 groups per row
  int e = (t & 255) << 2;
  float4 a = *reinterpret_cast<const float4*>(table + (size_t)ctx[n] * EMB + e);
  float4 b = *reinterpret_cast<const float4*>(pos   + (size_t)n * EMB + e);
  float4 r = {a.x + b.x, a.y + b.y, a.z + b.z, a.w + b.w};
  *reinterpret_cast<float4*>(z + (size_t)n * EMB + e) = r;
}

// ---------------- tiled f32 GEMM: C = act(A@B + bias) + res ----------------
// A: f32 [M x K] row-major, B: f32 [K x Nc] row-major, C: f32 [M x Nc]
// BM=64, BK=16; 256 threads. grid.z offsets B and C (batched heads).
// res may alias C (element-wise read-then-write by the owning thread only).
template<int BN>
__global__ __launch_bounds__(256) void gemm_kernel(
    const float* __restrict__ A, const float* __restrict__ B, float* C,
    const float* __restrict__ bias, const float* res,
    int K, int Nc, long sBz, long sCz, int leaky)
{
  constexpr int BM = 64, BK = 16, TM = 4;
  constexpr int TN = (BN == 64) ? 4 : 2;
  __shared__ float As[BK][BM];
  __shared__ float Bs[BK][BN];
  int tid = threadIdx.x;
  B += (size_t)blockIdx.z * sBz;
  C += (size_t)blockIdx.z * sCz;
  int row0 = blockIdx.y * BM;
  int col0 = blockIdx.x * BN;
  int tx = tid % (BN / TN);
  int ty = tid / (BN / TN);
  float acc[TM][TN] = {};
  int ar = tid >> 2;            // 0..63
  int ak = (tid & 3) << 2;      // 0,4,8,12
  for (int k0 = 0; k0 < K; k0 += BK) {
    float4 av = *reinterpret_cast<const float4*>(A + (size_t)(row0 + ar) * K + k0 + ak);
    As[ak+0][ar] = av.x; As[ak+1][ar] = av.y; As[ak+2][ar] = av.z; As[ak+3][ar] = av.w;
    if (tid < BK * BN / 4) {
      int br = (tid * 4) / BN, bc = (tid * 4) % BN;
      float4 bv = *reinterpret_cast<const float4*>(B + (size_t)(k0 + br) * Nc + col0 + bc);
      Bs[br][bc+0] = bv.x; Bs[br][bc+1] = bv.y; Bs[br][bc+2] = bv.z; Bs[br][bc+3] = bv.w;
    }
    __syncthreads();
    #pragma unroll
    for (int k = 0; k < BK; k++) {
      float4 a4 = *reinterpret_cast<const float4*>(&As[k][ty * TM]);
      float a[4] = {a4.x, a4.y, a4.z, a4.w};
      float b[TN];
      if constexpr (TN == 4) {
        float4 b4 = *reinterpret_cast<const float4*>(&Bs[k][tx * TN]);
        b[0]=b4.x; b[1]=b4.y; b[2]=b4.z; b[3]=b4.w;
      } else {
        float2 b2 = *reinterpret_cast<const float2*>(&Bs[k][tx * TN]);
        b[0]=b2.x; b[1]=b2.y;
      }
      #pragma unroll
      for (int i = 0; i < TM; i++)
        #pragma unroll
        for (int j = 0; j < TN; j++)
          acc[i][j] = fmaf(a[i], b[j], acc[i][j]);
    }
    __syncthreads();
  }
  #pragma unroll
  for (int i = 0; i < TM; i++) {
    int r = row0 + ty * TM + i;
    #pragma unroll
    for (int j = 0; j < TN; j++) {
      int c = col0 + tx * TN + j;
      float v = acc[i][j];
      if (bias)  v += bias[c];
      if (leaky) v = v > 0.f ? v : 0.01f * v;
      if (res)   v += res[(size_t)r * Nc + c];
      C[(size_t)r * Nc + c] = v;
    }
  }
}

// ---------------- attention: flash-style, 64 queries/block, K/V tiles in LDS --
// Q,K,V: f32 [H][N][32]; O: f32 [N][H*32]
// Wave w owns queries q0+w*16 .. +15. Lane: query = q0+w*16+(lane%16),
// key-group jg = lane/16 handles keys j = jj*4+jg of each 64-key tile.
// Row stride 36 floats -> the 4 concurrent broadcast rows hit distinct banks.
__global__ __launch_bounds__(256) void attn_kernel(const float* __restrict__ Q,
    const float* __restrict__ K, const float* __restrict__ V, float* __restrict__ O)
{
  __shared__ float Ks[64][36];
  __shared__ float Vs[64][36];
  int tid = threadIdx.x;
  int lane = tid & 63, w = tid >> 6;
  int h = blockIdx.y;
  int qi = blockIdx.x * 64 + w * 16 + (lane & 15);
  int jg = lane >> 4;
  const float sc = 0.17677669529663687f;  // 1/sqrt(32)

  float q[32];
  {
    const float* qp = Q + ((size_t)h * NSEQ + qi) * HD;
    #pragma unroll
    for (int g = 0; g < 8; g++) {
      float4 v4 = *reinterpret_cast<const float4*>(qp + 4 * g);
      q[4*g]=v4.x; q[4*g+1]=v4.y; q[4*g+2]=v4.z; q[4*g+3]=v4.w;
    }
  }
  float m = -3.0e38f, s = 0.f, acc[32];
  #pragma unroll
  for (int v = 0; v < 32; v++) acc[v] = 0.f;

  for (int kt = 0; kt < NSEQ; kt += 64) {
    __syncthreads();   // protect LDS from overwrite while prior tile in use
    #pragma unroll
    for (int i = 0; i < 2; i++) {
      int idx = tid + i * 256;          // 0..511 float4 slots
      int r = idx >> 3, c = (idx & 7) << 2;
      float4 kv = *reinterpret_cast<const float4*>(K + ((size_t)h * NSEQ + kt + r) * HD + c);
      float4 vv = *reinterpret_cast<const float4*>(V + ((size_t)h * NSEQ + kt + r) * HD + c);
      *reinterpret_cast<float4*>(&Ks[r][c]) = kv;
      *reinterpret_cast<float4*>(&Vs[r][c]) = vv;
    }
    __syncthreads();

    float d[16];
    float tm = -3.0e38f;
    #pragma unroll
    for (int jj = 0; jj < 16; jj++) {
      int j = jj * 4 + jg;
      float dot = 0.f;
      #pragma unroll
      for (int g = 0; g < 8; g++) {
        float4 kv = *reinterpret_cast<const float4*>(&Ks[j][4*g]);
        dot = fmaf(q[4*g],   kv.x, dot);
        dot = fmaf(q[4*g+1], kv.y, dot);
        dot = fmaf(q[4*g+2], kv.z, dot);
        dot = fmaf(q[4*g+3], kv.w, dot);
      }
      d[jj] = dot * sc;
      tm = fmaxf(tm, d[jj]);
    }
    tm = fmaxf(tm, __shfl_xor(tm, 16));
    tm = fmaxf(tm, __shfl_xor(tm, 32));
    float mN = fmaxf(m, tm);
    float corr = __expf(m - mN);        // first tile: exp(-huge)=0
    float ls = 0.f;
    #pragma unroll
    for (int jj = 0; jj < 16; jj++) { d[jj] = __expf(d[jj] - mN); ls += d[jj]; }
    ls += __shfl_xor(ls, 16);
    ls += __shfl_xor(ls, 32);
    s = s * corr + ls;
    #pragma unroll
    for (int v = 0; v < 32; v++) acc[v] *= corr;
    #pragma unroll
    for (int jj = 0; jj < 16; jj++) {
      int j = jj * 4 + jg;
      float p = d[jj];
      #pragma unroll
      for (int g = 0; g < 8; g++) {
        float4 vv = *reinterpret_cast<const float4*>(&Vs[j][4*g]);
        acc[4*g]   = fmaf(p, vv.x, acc[4*g]);
        acc[4*g+1] = fmaf(p, vv.y, acc[4*g+1]);
        acc[4*g+2] = fmaf(p, vv.z, acc[4*g+2]);
        acc[4*g+3] = fmaf(p, vv.w, acc[4*g+3]);
      }
    }
    m = mN;
  }
  // merge the 4 key-groups (m, s already uniform across them)
  #pragma unroll
  for (int v = 0; v < 32; v++) {
    acc[v] += __shfl_xor(acc[v], 16);
    acc[v] += __shfl_xor(acc[v], 32);
  }
  if (jg == 0) {
    float inv = 1.f / s;
    float* op = O + (size_t)qi * HV + h * HD;
    #pragma unroll
    for (int g = 0; g < 8; g++) {
      float4 o4 = {acc[4*g]*inv, acc[4*g+1]*inv, acc[4*g+2]*inv, acc[4*g+3]*inv};
      *reinterpret_cast<float4*>(op + 4 * g) = o4;
    }
  }
}

// ---------------- layernorm over dim 1, unbiased std (ddof=1), no eps --------
__global__ __launch_bounds__(256) void ln_kernel(const float* in, float* out){
  __shared__ float sm[8];
  int row = blockIdx.x, tid = threadIdx.x;
  float4 x = reinterpret_cast<const float4*>(in + (size_t)row * EMB)[tid];
  float s = x.x + x.y + x.z + x.w;
  #pragma unroll
  for (int o = 32; o > 0; o >>= 1) s += __shfl_down(s, o);
  int wid = tid >> 6, lane = tid & 63;
  if (lane == 0) sm[wid] = s;
  __syncthreads();
  float mean = (sm[0] + sm[1] + sm[2] + sm[3]) * (1.f / EMB);
  float dx = x.x - mean, dy = x.y - mean, dz = x.z - mean, dw = x.w - mean;
  float qs = dx*dx + dy*dy + dz*dz + dw*dw;
  #pragma unroll
  for (int o = 32; o > 0; o >>= 1) qs += __shfl_down(qs, o);
  if (lane == 0) sm[4 + wid] = qs;
  __syncthreads();
  float var = (sm[4] + sm[5] + sm[6] + sm[7]) * (1.f / (EMB - 1));
  float inv = rsqrtf(var);
  float4 y = {dx * inv, dy * inv, dz * inv, dw * inv};
  reinterpret_cast<float4*>(out + (size_t)row * EMB)[tid] = y;
}

extern "C" void kernel_launch(void* const* d_in, const int* in_sizes, int n_in,
                              void* d_out, int out_size, void* d_ws, size_t ws_size,
                              hipStream_t stream)
{
  const int*   ctx   = (const int*)d_in[0];
  const float* table = (const float*)d_in[1];
  const float* pos   = (const float*)d_in[2];
  const float* Wq    = (const float*)d_in[3];
  const float* Wk    = (const float*)d_in[4];
  const float* Wv    = (const float*)d_in[5];
  const float* Wo    = (const float*)d_in[6];
  const float* W1    = (const float*)d_in[7];
  const float* b1    = (const float*)d_in[8];
  const float* W2    = (const float*)d_in[9];
  const float* b2    = (const float*)d_in[10];

  // residual stream z lives in d_out (f32 [N][E], 16 MB)
  float* z = (float*)d_out;

  char* ws = (char*)d_ws;
  const size_t MB = 1u << 20;
  // ws layout (48 MB):
  //   [0,16)  an  f32 [N][E]
  //   [16,24) q   f32 [H][N][32]
  //   [24,32) k   f32 [H][N][32]
  //   [32,40) v   f32 [H][N][32]
  //   [40,48) o   f32 [N][512]
  //   h1 f32 [N][2048] = [16,48)  (overlaps q/k/v/o after they're consumed)
  float* an = (float*)(ws);
  float* qb = (float*)(ws + 16 * MB);
  float* kb = (float*)(ws + 24 * MB);
  float* vb = (float*)(ws + 32 * MB);
  float* ob = (float*)(ws + 40 * MB);
  float* h1 = (float*)(ws + 16 * MB);

  embed_kernel<<<NSEQ * EMB / 4 / 256, 256, 0, stream>>>(ctx, table, pos, z);

  for (int l = 0; l < NL; l++) {
    const float* wq  = Wq + (size_t)l * NH * EMB * HD;
    const float* wk  = Wk + (size_t)l * NH * EMB * HD;
    const float* wv  = Wv + (size_t)l * NH * EMB * HD;
    const float* wo  = Wo + (size_t)l * HV * EMB;
    const float* w1  = W1 + (size_t)l * EMB * FF;
    const float* bb1 = b1 + (size_t)l * FF;
    const float* w2  = W2 + (size_t)l * FF * EMB;
    const float* bb2 = b2 + (size_t)l * EMB;

    // Q/K/V: batched per-head GEMM [N x E] @ [E x 32] -> f32 [H][N][32]
    gemm_kernel<32><<<dim3(1, NSEQ/64, NH), 256, 0, stream>>>(
        z, wq, qb, nullptr, nullptr, EMB, HD, (long)EMB * HD, (long)NSEQ * HD, 0);
    gemm_kernel<32><<<dim3(1, NSEQ/64, NH), 256, 0, stream>>>(
        z, wk, kb, nullptr, nullptr, EMB, HD, (long)EMB * HD, (long)NSEQ * HD, 0);
    gemm_kernel<32><<<dim3(1, NSEQ/64, NH), 256, 0, stream>>>(
        z, wv, vb, nullptr, nullptr, EMB, HD, (long)EMB * HD, (long)NSEQ * HD, 0);

    attn_kernel<<<dim3(NSEQ/64, NH), 256, 0, stream>>>(qb, kb, vb, ob);

    // z <- z + o@Wo (in-place residual), then an = LN(z)
    gemm_kernel<64><<<dim3(EMB/64, NSEQ/64, 1), 256, 0, stream>>>(
        ob, wo, z, nullptr, z, HV, EMB, 0, 0, 0);
    ln_kernel<<<NSEQ, 256, 0, stream>>>(z, an);

    // h1 = leaky(an@W1 + b1)
    gemm_kernel<64><<<dim3(FF/64, NSEQ/64, 1), 256, 0, stream>>>(
        an, w1, h1, bb1, nullptr, EMB, FF, 0, 0, 1);
    // z = h1@W2 + b2 + an, then z = LN(z) in place
    gemm_kernel<64><<<dim3(EMB/64, NSEQ/64, 1), 256, 0, stream>>>(
        h1, w2, z, bb2, an, FF, EMB, 0, 0, 0);
    ln_kernel<<<NSEQ, 256, 0, stream>>>(z, z);
  }
}

// Round 4
// 4830.995 us; speedup vs baseline: 1.9353x; 1.9353x over previous
//
#include <hip/hip_runtime.h>
#include <hip/hip_bf16.h>

typedef _Float16 f16;
typedef __attribute__((ext_vector_type(8))) _Float16 f16x8;  // MFMA A/B frag
typedef __attribute__((ext_vector_type(4))) float f4v;       // MFMA acc

constexpr int NSEQ = 4096;
constexpr int EMB  = 1024;
constexpr int NH   = 16;
constexpr int HD   = 32;       // head dim
constexpr int NL   = 6;
constexpr int HV   = NH * HD;  // 512
constexpr int FF   = 2 * EMB;  // 2048
constexpr int QKVW = 3 * HV;   // 1536 (q|k|v concatenated per row)

__device__ __forceinline__ void h8_to_f32(uint4 u, float* f){
  union { uint4 u; f16 h[8]; } cv; cv.u = u;
  #pragma unroll
  for (int i = 0; i < 8; i++) f[i] = (float)cv.h[i];
}

// ---------------- embedding: z = table[ctx] + pos; also f16 copy ----------
__global__ __launch_bounds__(256) void embed_kernel(const int* __restrict__ ctx,
    const float* __restrict__ table, const float* __restrict__ pos,
    float* __restrict__ z, f16* __restrict__ zh){
  int t = blockIdx.x * 256 + threadIdx.x;
  int n = t >> 8;
  int e = (t & 255) << 2;
  float4 a = *reinterpret_cast<const float4*>(table + (size_t)ctx[n] * EMB + e);
  float4 b = *reinterpret_cast<const float4*>(pos   + (size_t)n * EMB + e);
  float4 r = {a.x + b.x, a.y + b.y, a.z + b.z, a.w + b.w};
  *reinterpret_cast<float4*>(z + (size_t)n * EMB + e) = r;
  f16 o[4] = {(f16)r.x, (f16)r.y, (f16)r.z, (f16)r.w};
  uint2 u; __builtin_memcpy(&u, o, 8);
  *reinterpret_cast<uint2*>(zh + (size_t)n * EMB + e) = u;
}

// ------------- transpose-convert: out[n*K + k] = (f16)in[k*N + n] ----------
// grid: (K/32, N/32, Z). LDS-tiled, coalesced both sides.
__global__ __launch_bounds__(256) void convT_kernel(const float* __restrict__ in,
    f16* __restrict__ out, int K, int N, long sInZ, long sOutZ){
  __shared__ float t[32][33];
  in  += (size_t)blockIdx.z * sInZ;
  out += (size_t)blockIdx.z * sOutZ;
  int k0 = blockIdx.x * 32, n0 = blockIdx.y * 32;
  int r = threadIdx.x >> 5, c = threadIdx.x & 31;
  #pragma unroll
  for (int i = 0; i < 4; i++)
    t[r + i*8][c] = in[(size_t)(k0 + r + i*8) * N + n0 + c];
  __syncthreads();
  #pragma unroll
  for (int i = 0; i < 4; i++)
    out[(size_t)(n0 + r + i*8) * K + k0 + c] = (f16)t[c][r + i*8];
}

// ---------------- MFMA GEMM: C = act(A @ Bt^T + bias) + res ----------------
// A: f16 [M x K] row-major. Bt: f16 [N x K] row-major (B transposed).
// C: CT [M x N]. 128x128 tile, BK=32, 4 waves (2x2 of 64x64).
// 16x16x32 f16 MFMA; A/B frags: lane holds row (lane&15), k = quad*8..+7.
// C/D: col = lane&15, row = quad*4 + reg   [m89/m91-verified, dtype-indep].
template<typename CT>
__global__ __launch_bounds__(256) void gemm_mfma(
    const f16* __restrict__ A, const f16* __restrict__ Bt, CT* C,
    const float* __restrict__ bias, const float* res,
    int K, int Nc, int leaky)
{
  __shared__ f16 Ash[128][40];   // pad 32->40 (80B): 2-way bank alias = free
  __shared__ f16 Bsh[128][40];
  int tid = threadIdx.x;
  int lane = tid & 63, w = tid >> 6;
  int wm = w & 1, wn = w >> 1;
  int l16 = lane & 15, quad = lane >> 4;
  int row0 = blockIdx.y * 128, col0 = blockIdx.x * 128;

  f4v acc[4][4];
  #pragma unroll
  for (int i = 0; i < 4; i++)
    #pragma unroll
    for (int j = 0; j < 4; j++) acc[i][j] = {0.f, 0.f, 0.f, 0.f};

  int sr = tid >> 1;            // staging row 0..127
  int sc = (tid & 1) * 16;      // f16 col 0 or 16

  for (int k0 = 0; k0 < K; k0 += 32) {
    const uint4* ag = reinterpret_cast<const uint4*>(A  + (size_t)(row0 + sr) * K + k0 + sc);
    const uint4* bg = reinterpret_cast<const uint4*>(Bt + (size_t)(col0 + sr) * K + k0 + sc);
    uint4 a0 = ag[0], a1 = ag[1];
    uint4 b0 = bg[0], b1 = bg[1];
    __syncthreads();                       // prior tile fully consumed
    *reinterpret_cast<uint4*>(&Ash[sr][sc])     = a0;
    *reinterpret_cast<uint4*>(&Ash[sr][sc + 8]) = a1;
    *reinterpret_cast<uint4*>(&Bsh[sr][sc])     = b0;
    *reinterpret_cast<uint4*>(&Bsh[sr][sc + 8]) = b1;
    __syncthreads();
    f16x8 af[4], bf[4];
    #pragma unroll
    for (int mt = 0; mt < 4; mt++)
      af[mt] = *reinterpret_cast<const f16x8*>(&Ash[wm*64 + mt*16 + l16][quad*8]);
    #pragma unroll
    for (int nt = 0; nt < 4; nt++)
      bf[nt] = *reinterpret_cast<const f16x8*>(&Bsh[wn*64 + nt*16 + l16][quad*8]);
    #pragma unroll
    for (int mt = 0; mt < 4; mt++)
      #pragma unroll
      for (int nt = 0; nt < 4; nt++)
        acc[mt][nt] = __builtin_amdgcn_mfma_f32_16x16x32_f16(af[mt], bf[nt], acc[mt][nt], 0, 0, 0);
  }

  #pragma unroll
  for (int mt = 0; mt < 4; mt++) {
    #pragma unroll
    for (int nt = 0; nt < 4; nt++) {
      int ccol = col0 + wn*64 + nt*16 + l16;
      float bv = bias ? bias[ccol] : 0.f;
      #pragma unroll
      for (int reg = 0; reg < 4; reg++) {
        int crow = row0 + wm*64 + mt*16 + quad*4 + reg;
        float v = acc[mt][nt][reg] + bv;
        if (leaky) v = v > 0.f ? v : 0.01f * v;
        if (res)   v += res[(size_t)crow * Nc + ccol];
        if constexpr (sizeof(CT) == 2) C[(size_t)crow * Nc + ccol] = (f16)v;
        else                           C[(size_t)crow * Nc + ccol] = v;
      }
    }
  }
}

// ---------------- attention: flash-style, f16 QKV in, f16 O out ------------
// qkv: f16 [N][1536] rows = q|k|v sections, each [H][32].
// O: f16 [N][512]. Internal math f32 (round-2-verified structure).
__global__ __launch_bounds__(256) void attn_kernel(const f16* __restrict__ qkv,
    f16* __restrict__ O)
{
  __shared__ float Ks[64][36];
  __shared__ float Vs[64][36];
  int tid = threadIdx.x;
  int lane = tid & 63, w = tid >> 6;
  int h = blockIdx.y;
  int qi = blockIdx.x * 64 + w * 16 + (lane & 15);
  int jg = lane >> 4;
  const float sc = 0.17677669529663687f;  // 1/sqrt(32)

  float q[32];
  {
    const uint4* qp = reinterpret_cast<const uint4*>(qkv + (size_t)qi * QKVW + h * HD);
    #pragma unroll
    for (int g = 0; g < 4; g++) h8_to_f32(qp[g], q + 8 * g);
  }
  float m = -3.0e38f, s = 0.f, acc[32];
  #pragma unroll
  for (int v = 0; v < 32; v++) acc[v] = 0.f;

  int r = tid >> 2, part = tid & 3;       // staging: row, quarter (8 f16 each)
  for (int kt = 0; kt < NSEQ; kt += 64) {
    __syncthreads();
    #pragma unroll
    for (int i = 0; i < 2; i++) {         // i=0 -> K (off 512), i=1 -> V (off 1024)
      const uint4* src = reinterpret_cast<const uint4*>(
          qkv + (size_t)(kt + r) * QKVW + (i ? 2 * HV : HV) + h * HD + part * 8);
      float f[8]; h8_to_f32(*src, f);
      float* dst = i ? &Vs[r][part * 8] : &Ks[r][part * 8];
      *reinterpret_cast<float4*>(dst)     = {f[0], f[1], f[2], f[3]};
      *reinterpret_cast<float4*>(dst + 4) = {f[4], f[5], f[6], f[7]};
    }
    __syncthreads();

    float d[16];
    float tm = -3.0e38f;
    #pragma unroll
    for (int jj = 0; jj < 16; jj++) {
      int j = jj * 4 + jg;
      float dot = 0.f;
      #pragma unroll
      for (int g = 0; g < 8; g++) {
        float4 kv = *reinterpret_cast<const float4*>(&Ks[j][4*g]);
        dot = fmaf(q[4*g],   kv.x, dot);
        dot = fmaf(q[4*g+1], kv.y, dot);
        dot = fmaf(q[4*g+2], kv.z, dot);
        dot = fmaf(q[4*g+3], kv.w, dot);
      }
      d[jj] = dot * sc;
      tm = fmaxf(tm, d[jj]);
    }
    tm = fmaxf(tm, __shfl_xor(tm, 16));
    tm = fmaxf(tm, __shfl_xor(tm, 32));
    float mN = fmaxf(m, tm);
    float corr = __expf(m - mN);
    float ls = 0.f;
    #pragma unroll
    for (int jj = 0; jj < 16; jj++) { d[jj] = __expf(d[jj] - mN); ls += d[jj]; }
    ls += __shfl_xor(ls, 16);
    ls += __shfl_xor(ls, 32);
    s = s * corr + ls;
    #pragma unroll
    for (int v = 0; v < 32; v++) acc[v] *= corr;
    #pragma unroll
    for (int jj = 0; jj < 16; jj++) {
      int j = jj * 4 + jg;
      float p = d[jj];
      #pragma unroll
      for (int g = 0; g < 8; g++) {
        float4 vv = *reinterpret_cast<const float4*>(&Vs[j][4*g]);
        acc[4*g]   = fmaf(p, vv.x, acc[4*g]);
        acc[4*g+1] = fmaf(p, vv.y, acc[4*g+1]);
        acc[4*g+2] = fmaf(p, vv.z, acc[4*g+2]);
        acc[4*g+3] = fmaf(p, vv.w, acc[4*g+3]);
      }
    }
    m = mN;
  }
  #pragma unroll
  for (int v = 0; v < 32; v++) {
    acc[v] += __shfl_xor(acc[v], 16);
    acc[v] += __shfl_xor(acc[v], 32);
  }
  if (jg == 0) {
    float inv = 1.f / s;
    f16 ob[32];
    #pragma unroll
    for (int v = 0; v < 32; v++) ob[v] = (f16)(acc[v] * inv);
    uint4 u[4]; __builtin_memcpy(u, ob, 64);
    uint4* op = reinterpret_cast<uint4*>(O + (size_t)qi * HV + h * HD);
    #pragma unroll
    for (int g = 0; g < 4; g++) op[g] = u[g];
  }
}

// ------------- layernorm (dim 1, ddof=1, no eps) + f16 copy ----------------
__global__ __launch_bounds__(256) void ln_kernel(const float* in, float* out,
                                                 f16* __restrict__ outh){
  __shared__ float sm[8];
  int row = blockIdx.x, tid = threadIdx.x;
  float4 x = reinterpret_cast<const float4*>(in + (size_t)row * EMB)[tid];
  float s = x.x + x.y + x.z + x.w;
  #pragma unroll
  for (int o = 32; o > 0; o >>= 1) s += __shfl_down(s, o);
  int wid = tid >> 6, lane = tid & 63;
  if (lane == 0) sm[wid] = s;
  __syncthreads();
  float mean = (sm[0] + sm[1] + sm[2] + sm[3]) * (1.f / EMB);
  float dx = x.x - mean, dy = x.y - mean, dz = x.z - mean, dw = x.w - mean;
  float qs = dx*dx + dy*dy + dz*dz + dw*dw;
  #pragma unroll
  for (int o = 32; o > 0; o >>= 1) qs += __shfl_down(qs, o);
  if (lane == 0) sm[4 + wid] = qs;
  __syncthreads();
  float var = (sm[4] + sm[5] + sm[6] + sm[7]) * (1.f / (EMB - 1));
  float inv = rsqrtf(var);
  float4 y = {dx * inv, dy * inv, dz * inv, dw * inv};
  reinterpret_cast<float4*>(out + (size_t)row * EMB)[tid] = y;
  f16 o4[4] = {(f16)y.x, (f16)y.y, (f16)y.z, (f16)y.w};
  uint2 u; __builtin_memcpy(&u, o4, 8);
  reinterpret_cast<uint2*>(outh + (size_t)row * EMB)[tid] = u;
}

extern "C" void kernel_launch(void* const* d_in, const int* in_sizes, int n_in,
                              void* d_out, int out_size, void* d_ws, size_t ws_size,
                              hipStream_t stream)
{
  const int*   ctx   = (const int*)d_in[0];
  const float* table = (const float*)d_in[1];
  const float* pos   = (const float*)d_in[2];
  const float* Wq    = (const float*)d_in[3];
  const float* Wk    = (const float*)d_in[4];
  const float* Wv    = (const float*)d_in[5];
  const float* Wo    = (const float*)d_in[6];
  const float* W1    = (const float*)d_in[7];
  const float* b1    = (const float*)d_in[8];
  const float* W2    = (const float*)d_in[9];
  const float* b2    = (const float*)d_in[10];

  float* z = (float*)d_out;                 // residual stream f32 [N][E]

  char* ws = (char*)d_ws;
  const size_t MB = 1u << 20;
  // ws layout (52 MB):
  //  [0,16)   an    f32 [N][E]
  //  [16,24)  anh   f16 [N][E]
  //  [24,32)  zh    f16 [N][E]
  //  [32,44)  qkvh  f16 [N][1536]   } h1h f16 [N][2048] overlaps [32,48)
  //  [44,48)  Oh    f16 [N][512]    }
  //  [48,52)  wbuf  f16 (<=4 MB: qkvT 3MB / WoT 1MB / W1T 4MB / W2T 4MB)
  float* an   = (float*)(ws);
  f16*   anh  = (f16*)  (ws + 16 * MB);
  f16*   zh   = (f16*)  (ws + 24 * MB);
  f16*   qkvh = (f16*)  (ws + 32 * MB);
  f16*   Oh   = (f16*)  (ws + 44 * MB);
  f16*   h1h  = (f16*)  (ws + 32 * MB);
  f16*   wbuf = (f16*)  (ws + 48 * MB);

  embed_kernel<<<NSEQ * EMB / 4 / 256, 256, 0, stream>>>(ctx, table, pos, z, zh);

  for (int l = 0; l < NL; l++) {
    const float* wq  = Wq + (size_t)l * NH * EMB * HD;
    const float* wk  = Wk + (size_t)l * NH * EMB * HD;
    const float* wv  = Wv + (size_t)l * NH * EMB * HD;
    const float* wo  = Wo + (size_t)l * HV * EMB;
    const float* w1  = W1 + (size_t)l * EMB * FF;
    const float* bb1 = b1 + (size_t)l * FF;
    const float* w2  = W2 + (size_t)l * FF * EMB;
    const float* bb2 = b2 + (size_t)l * EMB;

    // qkvT rows: [0,512)=Q, [512,1024)=K, [1024,1536)=V; row = sec*512+h*32+v
    convT_kernel<<<dim3(EMB/32, 1, NH), 256, 0, stream>>>(
        wq, wbuf + (size_t)0 * HV * EMB, EMB, HD, (long)EMB * HD, (long)HD * EMB);
    convT_kernel<<<dim3(EMB/32, 1, NH), 256, 0, stream>>>(
        wk, wbuf + (size_t)1 * HV * EMB, EMB, HD, (long)EMB * HD, (long)HD * EMB);
    convT_kernel<<<dim3(EMB/32, 1, NH), 256, 0, stream>>>(
        wv, wbuf + (size_t)2 * HV * EMB, EMB, HD, (long)EMB * HD, (long)HD * EMB);
    // qkvh[N][1536] = zh @ qkvT^T
    gemm_mfma<f16><<<dim3(QKVW/128, NSEQ/128), 256, 0, stream>>>(
        zh, wbuf, qkvh, nullptr, nullptr, EMB, QKVW, 0);

    attn_kernel<<<dim3(NSEQ/64, NH), 256, 0, stream>>>(qkvh, Oh);

    // z += Oh @ Wo : WoT [1024][512]
    convT_kernel<<<dim3(HV/32, EMB/32, 1), 256, 0, stream>>>(
        wo, wbuf, HV, EMB, 0, 0);
    gemm_mfma<float><<<dim3(EMB/128, NSEQ/128), 256, 0, stream>>>(
        Oh, wbuf, z, nullptr, z, HV, EMB, 0);
    ln_kernel<<<NSEQ, 256, 0, stream>>>(z, an, anh);

    // h1 = leaky(an @ W1 + b1) : W1T [2048][1024]
    convT_kernel<<<dim3(EMB/32, FF/32, 1), 256, 0, stream>>>(
        w1, wbuf, EMB, FF, 0, 0);
    gemm_mfma<f16><<<dim3(FF/128, NSEQ/128), 256, 0, stream>>>(
        anh, wbuf, h1h, bb1, nullptr, EMB, FF, 1);
    // z = h1 @ W2 + b2 + an : W2T [1024][2048]
    convT_kernel<<<dim3(FF/32, EMB/32, 1), 256, 0, stream>>>(
        w2, wbuf, FF, EMB, 0, 0);
    gemm_mfma<float><<<dim3(EMB/128, NSEQ/128), 256, 0, stream>>>(
        h1h, wbuf, z, bb2, an, FF, EMB, 0);
    ln_kernel<<<NSEQ, 256, 0, stream>>>(z, z, zh);
  }
}

// Round 5
// 2731.783 us; speedup vs baseline: 3.4225x; 1.7684x over previous
//
#include <hip/hip_runtime.h>
#include <hip/hip_bf16.h>

typedef _Float16 f16;
typedef __attribute__((ext_vector_type(8))) _Float16 f16x8;  // MFMA A/B frag
typedef __attribute__((ext_vector_type(4))) float f4v;       // MFMA acc

constexpr int NSEQ = 4096;
constexpr int EMB  = 1024;
constexpr int NH   = 16;
constexpr int HD   = 32;       // head dim
constexpr int NL   = 6;
constexpr int HV   = NH * HD;  // 512
constexpr int FF   = 2 * EMB;  // 2048
constexpr int QKVW = 3 * HV;   // 1536 (q|k|v concatenated per row)

// ---------------- embedding: z = table[ctx] + pos; also f16 copy ----------
__global__ __launch_bounds__(256) void embed_kernel(const int* __restrict__ ctx,
    const float* __restrict__ table, const float* __restrict__ pos,
    float* __restrict__ z, f16* __restrict__ zh){
  int t = blockIdx.x * 256 + threadIdx.x;
  int n = t >> 8;
  int e = (t & 255) << 2;
  float4 a = *reinterpret_cast<const float4*>(table + (size_t)ctx[n] * EMB + e);
  float4 b = *reinterpret_cast<const float4*>(pos   + (size_t)n * EMB + e);
  float4 r = {a.x + b.x, a.y + b.y, a.z + b.z, a.w + b.w};
  *reinterpret_cast<float4*>(z + (size_t)n * EMB + e) = r;
  f16 o[4] = {(f16)r.x, (f16)r.y, (f16)r.z, (f16)r.w};
  uint2 u; __builtin_memcpy(&u, o, 8);
  *reinterpret_cast<uint2*>(zh + (size_t)n * EMB + e) = u;
}

// ------------- transpose-convert: out[n*K + k] = (f16)in[k*N + n] ----------
__global__ __launch_bounds__(256) void convT_kernel(const float* __restrict__ in,
    f16* __restrict__ out, int K, int N, long sInZ, long sOutZ){
  __shared__ float t[32][33];
  in  += (size_t)blockIdx.z * sInZ;
  out += (size_t)blockIdx.z * sOutZ;
  int k0 = blockIdx.x * 32, n0 = blockIdx.y * 32;
  int r = threadIdx.x >> 5, c = threadIdx.x & 31;
  #pragma unroll
  for (int i = 0; i < 4; i++)
    t[r + i*8][c] = in[(size_t)(k0 + r + i*8) * N + n0 + c];
  __syncthreads();
  #pragma unroll
  for (int i = 0; i < 4; i++)
    out[(size_t)(n0 + r + i*8) * K + k0 + c] = (f16)t[c][r + i*8];
}

// ---------------- MFMA GEMM: C = act(A @ Bt^T + bias) + res ----------------
// A: f16 [M x K] row-major. Bt: f16 [N x K] row-major (B transposed).
// 128x128 tile, BK=32, 4 waves (2x2 of 64x64). 16x16x32 f16 MFMA.
// C/D: col = lane&15, row = quad*4 + reg   [m89/m91-verified, dtype-indep].
template<typename CT>
__global__ __launch_bounds__(256) void gemm_mfma(
    const f16* __restrict__ A, const f16* __restrict__ Bt, CT* C,
    const float* __restrict__ bias, const float* res,
    int K, int Nc, int leaky)
{
  __shared__ f16 Ash[128][40];   // pad 32->40 (80B): 2-way bank alias = free
  __shared__ f16 Bsh[128][40];
  int tid = threadIdx.x;
  int lane = tid & 63, w = tid >> 6;
  int wm = w & 1, wn = w >> 1;
  int l16 = lane & 15, quad = lane >> 4;
  int row0 = blockIdx.y * 128, col0 = blockIdx.x * 128;

  f4v acc[4][4];
  #pragma unroll
  for (int i = 0; i < 4; i++)
    #pragma unroll
    for (int j = 0; j < 4; j++) acc[i][j] = {0.f, 0.f, 0.f, 0.f};

  int sr = tid >> 1;            // staging row 0..127
  int sc = (tid & 1) * 16;      // f16 col 0 or 16

  for (int k0 = 0; k0 < K; k0 += 32) {
    const uint4* ag = reinterpret_cast<const uint4*>(A  + (size_t)(row0 + sr) * K + k0 + sc);
    const uint4* bg = reinterpret_cast<const uint4*>(Bt + (size_t)(col0 + sr) * K + k0 + sc);
    uint4 a0 = ag[0], a1 = ag[1];
    uint4 b0 = bg[0], b1 = bg[1];
    __syncthreads();                       // prior tile fully consumed
    *reinterpret_cast<uint4*>(&Ash[sr][sc])     = a0;
    *reinterpret_cast<uint4*>(&Ash[sr][sc + 8]) = a1;
    *reinterpret_cast<uint4*>(&Bsh[sr][sc])     = b0;
    *reinterpret_cast<uint4*>(&Bsh[sr][sc + 8]) = b1;
    __syncthreads();
    f16x8 af[4], bf[4];
    #pragma unroll
    for (int mt = 0; mt < 4; mt++)
      af[mt] = *reinterpret_cast<const f16x8*>(&Ash[wm*64 + mt*16 + l16][quad*8]);
    #pragma unroll
    for (int nt = 0; nt < 4; nt++)
      bf[nt] = *reinterpret_cast<const f16x8*>(&Bsh[wn*64 + nt*16 + l16][quad*8]);
    #pragma unroll
    for (int mt = 0; mt < 4; mt++)
      #pragma unroll
      for (int nt = 0; nt < 4; nt++)
        acc[mt][nt] = __builtin_amdgcn_mfma_f32_16x16x32_f16(af[mt], bf[nt], acc[mt][nt], 0, 0, 0);
  }

  #pragma unroll
  for (int mt = 0; mt < 4; mt++) {
    #pragma unroll
    for (int nt = 0; nt < 4; nt++) {
      int ccol = col0 + wn*64 + nt*16 + l16;
      float bv = bias ? bias[ccol] : 0.f;
      #pragma unroll
      for (int reg = 0; reg < 4; reg++) {
        int crow = row0 + wm*64 + mt*16 + quad*4 + reg;
        float v = acc[mt][nt][reg] + bv;
        if (leaky) v = v > 0.f ? v : 0.01f * v;
        if (res)   v += res[(size_t)crow * Nc + ccol];
        if constexpr (sizeof(CT) == 2) C[(size_t)crow * Nc + ccol] = (f16)v;
        else                           C[(size_t)crow * Nc + ccol] = v;
      }
    }
  }
}

// ---------------- MFMA flash attention ------------------------------------
// qkv: f16 [N][1536] = q|k|v sections, each [H][32]. O: f16 [N][512].
// Block = 64 queries x 1 head; wave w owns queries q0..q0+15.
// Per 64-key tile: QK^T = 4 MFMA (Q A-frag in regs, K rows = B-frags from LDS),
// online softmax on C-layout scores (row=quad*4+reg, col=l16; row-reduce =
// shfl_xor 1/2/4/8 over l16 group), P -> per-wave LDS (C-layout write,
// A-layout b128 read), PV = 4 MFMA vs V^T staged transposed in LDS.
__global__ __launch_bounds__(256) void attn_mfma(const f16* __restrict__ qkv,
    f16* __restrict__ O)
{
  __shared__ f16 Ks[64][40];       // [key][dim], stride 40 (80B, 16B-aligned)
  __shared__ f16 Vt[32][72];       // [dim][key], stride 72 (144B, 16B-aligned)
  __shared__ f16 Ps[4][16][72];    // per-wave P [q][key]
  int tid = threadIdx.x;
  int lane = tid & 63, w = tid >> 6;
  int l16 = lane & 15, quad = lane >> 4;
  int h = blockIdx.y;
  int q0 = blockIdx.x * 64 + w * 16;
  const float sc = 0.17677669529663687f;   // 1/sqrt(32)

  // Q A-frag: lane holds Q[q0+l16][quad*8 .. +7], pre-scaled by 1/sqrt(32)
  f16x8 qf;
  {
    union { uint4 u; f16 h[8]; } qc;
    qc.u = *reinterpret_cast<const uint4*>(
        qkv + (size_t)(q0 + l16) * QKVW + h * HD + quad * 8);
    #pragma unroll
    for (int i = 0; i < 8; i++) qc.h[i] = (f16)((float)qc.h[i] * sc);
    __builtin_memcpy(&qf, qc.h, 16);
  }

  float m_[4], l_[4];
  #pragma unroll
  for (int r = 0; r < 4; r++) { m_[r] = -3.0e38f; l_[r] = 0.f; }
  f4v oacc[2];
  oacc[0] = {0.f,0.f,0.f,0.f}; oacc[1] = {0.f,0.f,0.f,0.f};

  int srow = tid >> 2, spart = tid & 3;    // staging: key row, 8-dim quarter
  for (int kt = 0; kt < NSEQ; kt += 64) {
    uint4 kreg = *reinterpret_cast<const uint4*>(
        qkv + (size_t)(kt + srow) * QKVW + HV + h * HD + spart * 8);
    uint4 vreg = *reinterpret_cast<const uint4*>(
        qkv + (size_t)(kt + srow) * QKVW + 2 * HV + h * HD + spart * 8);
    __syncthreads();                       // prior tile fully consumed
    *reinterpret_cast<uint4*>(&Ks[srow][spart * 8]) = kreg;
    {
      union { uint4 u; f16 h[8]; } vc; vc.u = vreg;
      #pragma unroll
      for (int i = 0; i < 8; i++) Vt[spart * 8 + i][srow] = vc.h[i];
    }
    __syncthreads();

    // QK^T: 4 key sub-tiles of 16
    f4v s4[4];
    #pragma unroll
    for (int t = 0; t < 4; t++) {
      f16x8 kf = *reinterpret_cast<const f16x8*>(&Ks[t * 16 + l16][quad * 8]);
      s4[t] = __builtin_amdgcn_mfma_f32_16x16x32_f16(qf, kf, (f4v){0.f,0.f,0.f,0.f}, 0, 0, 0);
    }
    // online softmax, per accumulator reg (row = quad*4+reg)
    float corr[4];
    #pragma unroll
    for (int r = 0; r < 4; r++) {
      float tm = fmaxf(fmaxf(s4[0][r], s4[1][r]), fmaxf(s4[2][r], s4[3][r]));
      tm = fmaxf(tm, __shfl_xor(tm, 1));
      tm = fmaxf(tm, __shfl_xor(tm, 2));
      tm = fmaxf(tm, __shfl_xor(tm, 4));
      tm = fmaxf(tm, __shfl_xor(tm, 8));
      float mN = fmaxf(m_[r], tm);
      corr[r] = __expf(m_[r] - mN);
      float ls = 0.f;
      #pragma unroll
      for (int t = 0; t < 4; t++) {
        float p = __expf(s4[t][r] - mN);
        s4[t][r] = p;
        ls += p;
      }
      ls += __shfl_xor(ls, 1);
      ls += __shfl_xor(ls, 2);
      ls += __shfl_xor(ls, 4);
      ls += __shfl_xor(ls, 8);
      l_[r] = l_[r] * corr[r] + ls;
      m_[r] = mN;
    }
    // P -> LDS (f16), then rescale O accumulators
    #pragma unroll
    for (int t = 0; t < 4; t++)
      #pragma unroll
      for (int r = 0; r < 4; r++)
        Ps[w][quad * 4 + r][t * 16 + l16] = (f16)s4[t][r];
    #pragma unroll
    for (int vt = 0; vt < 2; vt++)
      #pragma unroll
      for (int r = 0; r < 4; r++)
        oacc[vt][r] *= corr[r];
    // PV: A-frag = P rows (A-layout), B-frag = V^T rows
    #pragma unroll
    for (int kc = 0; kc < 2; kc++) {
      f16x8 pf = *reinterpret_cast<const f16x8*>(&Ps[w][l16][kc * 32 + quad * 8]);
      #pragma unroll
      for (int vt = 0; vt < 2; vt++) {
        f16x8 vf = *reinterpret_cast<const f16x8*>(&Vt[vt * 16 + l16][kc * 32 + quad * 8]);
        oacc[vt] = __builtin_amdgcn_mfma_f32_16x16x32_f16(pf, vf, oacc[vt], 0, 0, 0);
      }
    }
  }
  // epilogue: O[q0+quad*4+r][h*32 + vt*16 + l16] = oacc/l
  #pragma unroll
  for (int vt = 0; vt < 2; vt++)
    #pragma unroll
    for (int r = 0; r < 4; r++) {
      int row = q0 + quad * 4 + r;
      O[(size_t)row * HV + h * HD + vt * 16 + l16] = (f16)(oacc[vt][r] / l_[r]);
    }
}

// ------------- layernorm (dim 1, ddof=1, no eps) + f16 copy ----------------
__global__ __launch_bounds__(256) void ln_kernel(const float* in, float* out,
                                                 f16* __restrict__ outh){
  __shared__ float sm[8];
  int row = blockIdx.x, tid = threadIdx.x;
  float4 x = reinterpret_cast<const float4*>(in + (size_t)row * EMB)[tid];
  float s = x.x + x.y + x.z + x.w;
  #pragma unroll
  for (int o = 32; o > 0; o >>= 1) s += __shfl_down(s, o);
  int wid = tid >> 6, lane = tid & 63;
  if (lane == 0) sm[wid] = s;
  __syncthreads();
  float mean = (sm[0] + sm[1] + sm[2] + sm[3]) * (1.f / EMB);
  float dx = x.x - mean, dy = x.y - mean, dz = x.z - mean, dw = x.w - mean;
  float qs = dx*dx + dy*dy + dz*dz + dw*dw;
  #pragma unroll
  for (int o = 32; o > 0; o >>= 1) qs += __shfl_down(qs, o);
  if (lane == 0) sm[4 + wid] = qs;
  __syncthreads();
  float var = (sm[4] + sm[5] + sm[6] + sm[7]) * (1.f / (EMB - 1));
  float inv = rsqrtf(var);
  float4 y = {dx * inv, dy * inv, dz * inv, dw * inv};
  reinterpret_cast<float4*>(out + (size_t)row * EMB)[tid] = y;
  f16 o4[4] = {(f16)y.x, (f16)y.y, (f16)y.z, (f16)y.w};
  uint2 u; __builtin_memcpy(&u, o4, 8);
  reinterpret_cast<uint2*>(outh + (size_t)row * EMB)[tid] = u;
}

extern "C" void kernel_launch(void* const* d_in, const int* in_sizes, int n_in,
                              void* d_out, int out_size, void* d_ws, size_t ws_size,
                              hipStream_t stream)
{
  const int*   ctx   = (const int*)d_in[0];
  const float* table = (const float*)d_in[1];
  const float* pos   = (const float*)d_in[2];
  const float* Wq    = (const float*)d_in[3];
  const float* Wk    = (const float*)d_in[4];
  const float* Wv    = (const float*)d_in[5];
  const float* Wo    = (const float*)d_in[6];
  const float* W1    = (const float*)d_in[7];
  const float* b1    = (const float*)d_in[8];
  const float* W2    = (const float*)d_in[9];
  const float* b2    = (const float*)d_in[10];

  float* z = (float*)d_out;                 // residual stream f32 [N][E]

  char* ws = (char*)d_ws;
  const size_t MB = 1u << 20;
  // ws layout (52 MB):
  //  [0,16)   an    f32 [N][E]
  //  [16,24)  anh   f16 [N][E]
  //  [24,32)  zh    f16 [N][E]
  //  [32,44)  qkvh  f16 [N][1536]   } h1h f16 [N][2048] overlaps [32,48)
  //  [44,48)  Oh    f16 [N][512]    }
  //  [48,52)  wbuf  f16 (<=4 MB: qkvT 3MB / WoT 1MB / W1T 4MB / W2T 4MB)
  float* an   = (float*)(ws);
  f16*   anh  = (f16*)  (ws + 16 * MB);
  f16*   zh   = (f16*)  (ws + 24 * MB);
  f16*   qkvh = (f16*)  (ws + 32 * MB);
  f16*   Oh   = (f16*)  (ws + 44 * MB);
  f16*   h1h  = (f16*)  (ws + 32 * MB);
  f16*   wbuf = (f16*)  (ws + 48 * MB);

  embed_kernel<<<NSEQ * EMB / 4 / 256, 256, 0, stream>>>(ctx, table, pos, z, zh);

  for (int l = 0; l < NL; l++) {
    const float* wq  = Wq + (size_t)l * NH * EMB * HD;
    const float* wk  = Wk + (size_t)l * NH * EMB * HD;
    const float* wv  = Wv + (size_t)l * NH * EMB * HD;
    const float* wo  = Wo + (size_t)l * HV * EMB;
    const float* w1  = W1 + (size_t)l * EMB * FF;
    const float* bb1 = b1 + (size_t)l * FF;
    const float* w2  = W2 + (size_t)l * FF * EMB;
    const float* bb2 = b2 + (size_t)l * EMB;

    // qkvT rows: [0,512)=Q, [512,1024)=K, [1024,1536)=V; row = sec*512+h*32+v
    convT_kernel<<<dim3(EMB/32, 1, NH), 256, 0, stream>>>(
        wq, wbuf + (size_t)0 * HV * EMB, EMB, HD, (long)EMB * HD, (long)HD * EMB);
    convT_kernel<<<dim3(EMB/32, 1, NH), 256, 0, stream>>>(
        wk, wbuf + (size_t)1 * HV * EMB, EMB, HD, (long)EMB * HD, (long)HD * EMB);
    convT_kernel<<<dim3(EMB/32, 1, NH), 256, 0, stream>>>(
        wv, wbuf + (size_t)2 * HV * EMB, EMB, HD, (long)EMB * HD, (long)HD * EMB);
    // qkvh[N][1536] = zh @ qkvT^T
    gemm_mfma<f16><<<dim3(QKVW/128, NSEQ/128), 256, 0, stream>>>(
        zh, wbuf, qkvh, nullptr, nullptr, EMB, QKVW, 0);

    attn_mfma<<<dim3(NSEQ/64, NH), 256, 0, stream>>>(qkvh, Oh);

    // z += Oh @ Wo : WoT [1024][512]
    convT_kernel<<<dim3(HV/32, EMB/32, 1), 256, 0, stream>>>(
        wo, wbuf, HV, EMB, 0, 0);
    gemm_mfma<float><<<dim3(EMB/128, NSEQ/128), 256, 0, stream>>>(
        Oh, wbuf, z, nullptr, z, HV, EMB, 0);
    ln_kernel<<<NSEQ, 256, 0, stream>>>(z, an, anh);

    // h1 = leaky(an @ W1 + b1) : W1T [2048][1024]
    convT_kernel<<<dim3(EMB/32, FF/32, 1), 256, 0, stream>>>(
        w1, wbuf, EMB, FF, 0, 0);
    gemm_mfma<f16><<<dim3(FF/128, NSEQ/128), 256, 0, stream>>>(
        anh, wbuf, h1h, bb1, nullptr, EMB, FF, 1);
    // z = h1 @ W2 + b2 + an : W2T [1024][2048]
    convT_kernel<<<dim3(FF/32, EMB/32, 1), 256, 0, stream>>>(
        w2, wbuf, FF, EMB, 0, 0);
    gemm_mfma<float><<<dim3(EMB/128, NSEQ/128), 256, 0, stream>>>(
        h1h, wbuf, z, bb2, an, FF, EMB, 0);
    ln_kernel<<<NSEQ, 256, 0, stream>>>(z, z, zh);
  }
}

// Round 6
// 2036.306 us; speedup vs baseline: 4.5914x; 1.3415x over previous
//
#include <hip/hip_runtime.h>
#include <hip/hip_bf16.h>

typedef _Float16 f16;
typedef __attribute__((ext_vector_type(8))) _Float16 f16x8;  // MFMA A/B frag
typedef __attribute__((ext_vector_type(4))) float f4v;       // MFMA acc

constexpr int NSEQ = 4096;
constexpr int EMB  = 1024;
constexpr int NH   = 16;
constexpr int HD   = 32;       // head dim
constexpr int NL   = 6;
constexpr int HV   = NH * HD;  // 512
constexpr int FF   = 2 * EMB;  // 2048
constexpr int QKVW = 3 * HV;   // 1536 (q|k|v concatenated per row)

// ---------------- embedding: z = table[ctx] + pos; also f16 copy ----------
__global__ __launch_bounds__(256) void embed_kernel(const int* __restrict__ ctx,
    const float* __restrict__ table, const float* __restrict__ pos,
    float* __restrict__ z, f16* __restrict__ zh){
  int t = blockIdx.x * 256 + threadIdx.x;
  int n = t >> 8;
  int e = (t & 255) << 2;
  float4 a = *reinterpret_cast<const float4*>(table + (size_t)ctx[n] * EMB + e);
  float4 b = *reinterpret_cast<const float4*>(pos   + (size_t)n * EMB + e);
  float4 r = {a.x + b.x, a.y + b.y, a.z + b.z, a.w + b.w};
  *reinterpret_cast<float4*>(z + (size_t)n * EMB + e) = r;
  f16 o[4] = {(f16)r.x, (f16)r.y, (f16)r.z, (f16)r.w};
  uint2 u; __builtin_memcpy(&u, o, 8);
  *reinterpret_cast<uint2*>(zh + (size_t)n * EMB + e) = u;
}

// ------------- transpose-convert: out[n*K + k] = (f16)in[k*N + n] ----------
__global__ __launch_bounds__(256) void convT_kernel(const float* __restrict__ in,
    f16* __restrict__ out, int K, int N, long sInZ, long sOutZ){
  __shared__ float t[32][33];
  in  += (size_t)blockIdx.z * sInZ;
  out += (size_t)blockIdx.z * sOutZ;
  int k0 = blockIdx.x * 32, n0 = blockIdx.y * 32;
  int r = threadIdx.x >> 5, c = threadIdx.x & 31;
  #pragma unroll
  for (int i = 0; i < 4; i++)
    t[r + i*8][c] = in[(size_t)(k0 + r + i*8) * N + n0 + c];
  __syncthreads();
  #pragma unroll
  for (int i = 0; i < 4; i++)
    out[(size_t)(n0 + r + i*8) * K + k0 + c] = (f16)t[c][r + i*8];
}

// ---------------- MFMA GEMM: C = act(A @ Bt^T + bias) + res ----------------
// A: f16 [M x K] row-major. Bt: f16 [N x K] row-major (B transposed).
// 128x128 tile, BK=32, 4 waves (2x2 of 64x64). 16x16x32 f16 MFMA.
// C/D: col = lane&15, row = quad*4 + reg   [m89/m91-verified, dtype-indep].
template<typename CT>
__global__ __launch_bounds__(256) void gemm_mfma(
    const f16* __restrict__ A, const f16* __restrict__ Bt, CT* C,
    const float* __restrict__ bias, const float* res,
    int K, int Nc, int leaky)
{
  __shared__ f16 Ash[128][40];   // pad 32->40 (80B): 2-way bank alias = free
  __shared__ f16 Bsh[128][40];
  int tid = threadIdx.x;
  int lane = tid & 63, w = tid >> 6;
  int wm = w & 1, wn = w >> 1;
  int l16 = lane & 15, quad = lane >> 4;
  int row0 = blockIdx.y * 128, col0 = blockIdx.x * 128;

  f4v acc[4][4];
  #pragma unroll
  for (int i = 0; i < 4; i++)
    #pragma unroll
    for (int j = 0; j < 4; j++) acc[i][j] = {0.f, 0.f, 0.f, 0.f};

  int sr = tid >> 1;            // staging row 0..127
  int sc = (tid & 1) * 16;      // f16 col 0 or 16

  for (int k0 = 0; k0 < K; k0 += 32) {
    const uint4* ag = reinterpret_cast<const uint4*>(A  + (size_t)(row0 + sr) * K + k0 + sc);
    const uint4* bg = reinterpret_cast<const uint4*>(Bt + (size_t)(col0 + sr) * K + k0 + sc);
    uint4 a0 = ag[0], a1 = ag[1];
    uint4 b0 = bg[0], b1 = bg[1];
    __syncthreads();                       // prior tile fully consumed
    *reinterpret_cast<uint4*>(&Ash[sr][sc])     = a0;
    *reinterpret_cast<uint4*>(&Ash[sr][sc + 8]) = a1;
    *reinterpret_cast<uint4*>(&Bsh[sr][sc])     = b0;
    *reinterpret_cast<uint4*>(&Bsh[sr][sc + 8]) = b1;
    __syncthreads();
    f16x8 af[4], bf[4];
    #pragma unroll
    for (int mt = 0; mt < 4; mt++)
      af[mt] = *reinterpret_cast<const f16x8*>(&Ash[wm*64 + mt*16 + l16][quad*8]);
    #pragma unroll
    for (int nt = 0; nt < 4; nt++)
      bf[nt] = *reinterpret_cast<const f16x8*>(&Bsh[wn*64 + nt*16 + l16][quad*8]);
    #pragma unroll
    for (int mt = 0; mt < 4; mt++)
      #pragma unroll
      for (int nt = 0; nt < 4; nt++)
        acc[mt][nt] = __builtin_amdgcn_mfma_f32_16x16x32_f16(af[mt], bf[nt], acc[mt][nt], 0, 0, 0);
  }

  #pragma unroll
  for (int mt = 0; mt < 4; mt++) {
    #pragma unroll
    for (int nt = 0; nt < 4; nt++) {
      int ccol = col0 + wn*64 + nt*16 + l16;
      float bv = bias ? bias[ccol] : 0.f;
      #pragma unroll
      for (int reg = 0; reg < 4; reg++) {
        int crow = row0 + wm*64 + mt*16 + quad*4 + reg;
        float v = acc[mt][nt][reg] + bv;
        if (leaky) v = v > 0.f ? v : 0.01f * v;
        if (res)   v += res[(size_t)crow * Nc + ccol];
        if constexpr (sizeof(CT) == 2) C[(size_t)crow * Nc + ccol] = (f16)v;
        else                           C[(size_t)crow * Nc + ccol] = v;
      }
    }
  }
}

// ---------------- MFMA flash attention, transposed-score formulation --------
// qkv: f16 [N][1536] = q|k|v sections, each [H][32]. O: f16 [N][512].
// Block = 64 q x 1 head, 4 waves x 16 q; 128-key tiles.
// S^T = K·Q   (A=K rows from Ks, B=Q frag): col=l16=QUERY, row=key.
//   -> per-lane softmax state (one query per lane): max = fmax tree + 2 shfl,
//      sum lane-local, P-write packs 4 consecutive keys (b64, 2-way free).
// O^T = Vt·P  (A=V^T rows, B=P rows): col=l16=query matches l/m state; no
//   cross-lane epilogue; 4 consecutive dims pack into one 8B store.
__global__ __launch_bounds__(256) void attn_mfma(const f16* __restrict__ qkv,
    f16* __restrict__ O)
{
  __shared__ f16 Ks[128][40];      // [key][dim]   stride 80B  (16B-aligned)
  __shared__ f16 Vt[32][136];      // [dim][key]   stride 272B (16B-aligned)
  __shared__ f16 Ps[4][16][136];   // per-wave P [q][key]
  int tid = threadIdx.x;
  int lane = tid & 63, w = tid >> 6;
  int l16 = lane & 15, quad = lane >> 4;
  int h = blockIdx.y;
  int q0 = blockIdx.x * 64 + w * 16;
  const float sc = 0.17677669529663687f;   // 1/sqrt(32)

  // Q frag (B operand): lane holds Q[q0+l16][quad*8..+7], pre-scaled
  f16x8 qf;
  {
    union { uint4 u; f16 e[8]; } qc;
    qc.u = *reinterpret_cast<const uint4*>(
        qkv + (size_t)(q0 + l16) * QKVW + h * HD + quad * 8);
    #pragma unroll
    for (int i = 0; i < 8; i++) qc.e[i] = (f16)((float)qc.e[i] * sc);
    __builtin_memcpy(&qf, qc.e, 16);
  }

  float m_ = -1e30f, lsum = 0.f;           // per-lane state for query l16
  f4v oaccT[2];
  oaccT[0] = {0.f,0.f,0.f,0.f}; oaccT[1] = {0.f,0.f,0.f,0.f};

  int ksrow = tid >> 1, ksc = (tid & 1) * 16;   // K staging: row, 16-f16 half
  int vkp = tid & 63, vdg = tid >> 6;           // V staging: key pair, dim grp

  for (int kt = 0; kt < NSEQ; kt += 128) {
    const f16* kp0 = qkv + (size_t)(kt + ksrow) * QKVW + HV + h * HD + ksc;
    uint4 ka = *reinterpret_cast<const uint4*>(kp0);
    uint4 kb = *reinterpret_cast<const uint4*>(kp0 + 8);
    const f16* vp0 = qkv + (size_t)(kt + 2 * vkp) * QKVW + 2 * HV + h * HD + vdg * 8;
    uint4 va = *reinterpret_cast<const uint4*>(vp0);
    uint4 vb = *reinterpret_cast<const uint4*>(vp0 + QKVW);
    __syncthreads();                       // prior tile fully consumed
    *reinterpret_cast<uint4*>(&Ks[ksrow][ksc])     = ka;
    *reinterpret_cast<uint4*>(&Ks[ksrow][ksc + 8]) = kb;
    {
      union { uint4 u; f16 e[8]; } c0, c1; c0.u = va; c1.u = vb;
      #pragma unroll
      for (int i = 0; i < 8; i++) {        // pack key pair -> one dword
        f16 pr[2] = {c0.e[i], c1.e[i]};
        unsigned d; __builtin_memcpy(&d, pr, 4);
        *reinterpret_cast<unsigned*>(&Vt[vdg * 8 + i][2 * vkp]) = d;
      }
    }
    __syncthreads();

    // S^T[key][q]: 8 key sub-tiles of 16
    f4v s4[8];
    #pragma unroll
    for (int t = 0; t < 8; t++) {
      f16x8 kf = *reinterpret_cast<const f16x8*>(&Ks[t * 16 + l16][quad * 8]);
      s4[t] = __builtin_amdgcn_mfma_f32_16x16x32_f16(kf, qf, (f4v){0.f,0.f,0.f,0.f}, 0, 0, 0);
    }
    // tile max for this query: lane-local tree + cross-quad (2 shfl)
    float tm = s4[0][0];
    #pragma unroll
    for (int t = 0; t < 8; t++)
      #pragma unroll
      for (int r = 0; r < 4; r++) tm = fmaxf(tm, s4[t][r]);
    tm = fmaxf(tm, __shfl_xor(tm, 16));
    tm = fmaxf(tm, __shfl_xor(tm, 32));
    float mN = fmaxf(m_, tm);
    float corr = __expf(m_ - mN);          // first tile: exp(-huge)=0
    m_ = mN;
    float ls = 0.f;
    #pragma unroll
    for (int t = 0; t < 8; t++) {          // exp + packed P write (4 keys)
      f16 pr[4];
      #pragma unroll
      for (int r = 0; r < 4; r++) {
        float p = __expf(s4[t][r] - mN);
        ls += p;
        pr[r] = (f16)p;
      }
      uint2 d; __builtin_memcpy(&d, pr, 8);
      *reinterpret_cast<uint2*>(&Ps[w][l16][t * 16 + quad * 4]) = d;
    }
    lsum = lsum * corr + ls;
    #pragma unroll
    for (int vt = 0; vt < 2; vt++)
      #pragma unroll
      for (int r = 0; r < 4; r++) oaccT[vt][r] *= corr;
    // O^T += Vt · P  (within-wave LDS dep on Ps: lgkmcnt only, no barrier)
    #pragma unroll
    for (int kc = 0; kc < 4; kc++) {
      f16x8 pf = *reinterpret_cast<const f16x8*>(&Ps[w][l16][kc * 32 + quad * 8]);
      #pragma unroll
      for (int vt = 0; vt < 2; vt++) {
        f16x8 vf = *reinterpret_cast<const f16x8*>(&Vt[vt * 16 + l16][kc * 32 + quad * 8]);
        oaccT[vt] = __builtin_amdgcn_mfma_f32_16x16x32_f16(vf, pf, oaccT[vt], 0, 0, 0);
      }
    }
  }
  // cross-quad sum of l (keys split across quads), then lane-local epilogue
  lsum += __shfl_xor(lsum, 16);
  lsum += __shfl_xor(lsum, 32);
  float inv = 1.f / lsum;
  #pragma unroll
  for (int vt = 0; vt < 2; vt++) {
    f16 ob[4];
    #pragma unroll
    for (int r = 0; r < 4; r++) ob[r] = (f16)(oaccT[vt][r] * inv);
    uint2 u; __builtin_memcpy(&u, ob, 8);
    *reinterpret_cast<uint2*>(
        O + (size_t)(q0 + l16) * HV + h * HD + vt * 16 + quad * 4) = u;
  }
}

// ------------- layernorm (dim 1, ddof=1, no eps) + f16 copy ----------------
__global__ __launch_bounds__(256) void ln_kernel(const float* in, float* out,
                                                 f16* __restrict__ outh){
  __shared__ float sm[8];
  int row = blockIdx.x, tid = threadIdx.x;
  float4 x = reinterpret_cast<const float4*>(in + (size_t)row * EMB)[tid];
  float s = x.x + x.y + x.z + x.w;
  #pragma unroll
  for (int o = 32; o > 0; o >>= 1) s += __shfl_down(s, o);
  int wid = tid >> 6, lane = tid & 63;
  if (lane == 0) sm[wid] = s;
  __syncthreads();
  float mean = (sm[0] + sm[1] + sm[2] + sm[3]) * (1.f / EMB);
  float dx = x.x - mean, dy = x.y - mean, dz = x.z - mean, dw = x.w - mean;
  float qs = dx*dx + dy*dy + dz*dz + dw*dw;
  #pragma unroll
  for (int o = 32; o > 0; o >>= 1) qs += __shfl_down(qs, o);
  if (lane == 0) sm[4 + wid] = qs;
  __syncthreads();
  float var = (sm[4] + sm[5] + sm[6] + sm[7]) * (1.f / (EMB - 1));
  float inv = rsqrtf(var);
  float4 y = {dx * inv, dy * inv, dz * inv, dw * inv};
  reinterpret_cast<float4*>(out + (size_t)row * EMB)[tid] = y;
  f16 o4[4] = {(f16)y.x, (f16)y.y, (f16)y.z, (f16)y.w};
  uint2 u; __builtin_memcpy(&u, o4, 8);
  reinterpret_cast<uint2*>(outh + (size_t)row * EMB)[tid] = u;
}

extern "C" void kernel_launch(void* const* d_in, const int* in_sizes, int n_in,
                              void* d_out, int out_size, void* d_ws, size_t ws_size,
                              hipStream_t stream)
{
  const int*   ctx   = (const int*)d_in[0];
  const float* table = (const float*)d_in[1];
  const float* pos   = (const float*)d_in[2];
  const float* Wq    = (const float*)d_in[3];
  const float* Wk    = (const float*)d_in[4];
  const float* Wv    = (const float*)d_in[5];
  const float* Wo    = (const float*)d_in[6];
  const float* W1    = (const float*)d_in[7];
  const float* b1    = (const float*)d_in[8];
  const float* W2    = (const float*)d_in[9];
  const float* b2    = (const float*)d_in[10];

  float* z = (float*)d_out;                 // residual stream f32 [N][E]

  char* ws = (char*)d_ws;
  const size_t MB = 1u << 20;
  // ws layout (52 MB):
  //  [0,16)   an    f32 [N][E]
  //  [16,24)  anh   f16 [N][E]
  //  [24,32)  zh    f16 [N][E]
  //  [32,44)  qkvh  f16 [N][1536]   } h1h f16 [N][2048] overlaps [32,48)
  //  [44,48)  Oh    f16 [N][512]    }
  //  [48,52)  wbuf  f16 (<=4 MB: qkvT 3MB / WoT 1MB / W1T 4MB / W2T 4MB)
  float* an   = (float*)(ws);
  f16*   anh  = (f16*)  (ws + 16 * MB);
  f16*   zh   = (f16*)  (ws + 24 * MB);
  f16*   qkvh = (f16*)  (ws + 32 * MB);
  f16*   Oh   = (f16*)  (ws + 44 * MB);
  f16*   h1h  = (f16*)  (ws + 32 * MB);
  f16*   wbuf = (f16*)  (ws + 48 * MB);

  embed_kernel<<<NSEQ * EMB / 4 / 256, 256, 0, stream>>>(ctx, table, pos, z, zh);

  for (int l = 0; l < NL; l++) {
    const float* wq  = Wq + (size_t)l * NH * EMB * HD;
    const float* wk  = Wk + (size_t)l * NH * EMB * HD;
    const float* wv  = Wv + (size_t)l * NH * EMB * HD;
    const float* wo  = Wo + (size_t)l * HV * EMB;
    const float* w1  = W1 + (size_t)l * EMB * FF;
    const float* bb1 = b1 + (size_t)l * FF;
    const float* w2  = W2 + (size_t)l * FF * EMB;
    const float* bb2 = b2 + (size_t)l * EMB;

    // qkvT rows: [0,512)=Q, [512,1024)=K, [1024,1536)=V; row = sec*512+h*32+v
    convT_kernel<<<dim3(EMB/32, 1, NH), 256, 0, stream>>>(
        wq, wbuf + (size_t)0 * HV * EMB, EMB, HD, (long)EMB * HD, (long)HD * EMB);
    convT_kernel<<<dim3(EMB/32, 1, NH), 256, 0, stream>>>(
        wk, wbuf + (size_t)1 * HV * EMB, EMB, HD, (long)EMB * HD, (long)HD * EMB);
    convT_kernel<<<dim3(EMB/32, 1, NH), 256, 0, stream>>>(
        wv, wbuf + (size_t)2 * HV * EMB, EMB, HD, (long)EMB * HD, (long)HD * EMB);
    // qkvh[N][1536] = zh @ qkvT^T
    gemm_mfma<f16><<<dim3(QKVW/128, NSEQ/128), 256, 0, stream>>>(
        zh, wbuf, qkvh, nullptr, nullptr, EMB, QKVW, 0);

    attn_mfma<<<dim3(NSEQ/64, NH), 256, 0, stream>>>(qkvh, Oh);

    // z += Oh @ Wo : WoT [1024][512]
    convT_kernel<<<dim3(HV/32, EMB/32, 1), 256, 0, stream>>>(
        wo, wbuf, HV, EMB, 0, 0);
    gemm_mfma<float><<<dim3(EMB/128, NSEQ/128), 256, 0, stream>>>(
        Oh, wbuf, z, nullptr, z, HV, EMB, 0);
    ln_kernel<<<NSEQ, 256, 0, stream>>>(z, an, anh);

    // h1 = leaky(an @ W1 + b1) : W1T [2048][1024]
    convT_kernel<<<dim3(EMB/32, FF/32, 1), 256, 0, stream>>>(
        w1, wbuf, EMB, FF, 0, 0);
    gemm_mfma<f16><<<dim3(FF/128, NSEQ/128), 256, 0, stream>>>(
        anh, wbuf, h1h, bb1, nullptr, EMB, FF, 1);
    // z = h1 @ W2 + b2 + an : W2T [1024][2048]
    convT_kernel<<<dim3(FF/32, EMB/32, 1), 256, 0, stream>>>(
        w2, wbuf, FF, EMB, 0, 0);
    gemm_mfma<float><<<dim3(EMB/128, NSEQ/128), 256, 0, stream>>>(
        h1h, wbuf, z, bb2, an, FF, EMB, 0);
    ln_kernel<<<NSEQ, 256, 0, stream>>>(z, z, zh);
  }
}